// Round 3
// baseline (1554.968 us; speedup 1.0000x reference)
//
#include <hip/hip_runtime.h>
#include <math.h>

// Problem constants
#define NRES 1024
#define CSD  384
#define CPD  128
#define CHD  16
#define NHD  12
#define PQD  4
#define PVD  8
#define COUT 2112   // H*(CP+CH+PV*4) = 12*176
#define LGP  1028   // lg row stride: NRES+4 pad -> bank shift 4 per head row

#define SQ_QK 0.14433756729740643f   // sqrt(1/48)
#define SQ_B  0.5773502691896258f    // sqrt(1/3)
#define SQ_PT 0.13608276348795434f   // sqrt(1/54)
#define INF_MASK 100000.0f

// ---------------------------------------------------------------------------
// K1: per-row projections q,k,v + rotated points qp,kp,vp
// 8 rows per block, 256 threads
// ---------------------------------------------------------------------------
__global__ __launch_bounds__(256) void k_proj(
    const float* __restrict__ s, const float* __restrict__ rots,
    const float* __restrict__ trans,
    const float* __restrict__ wq, const float* __restrict__ bq,
    const float* __restrict__ wkv, const float* __restrict__ bkv,
    const float* __restrict__ wqp, const float* __restrict__ bqp,
    const float* __restrict__ wkvp, const float* __restrict__ bkvp,
    float* __restrict__ q, float* __restrict__ k, float* __restrict__ v,
    float* __restrict__ qp, float* __restrict__ kp, float* __restrict__ vp)
{
    const int R = 8;
    __shared__ float sld[R][CSD];     // 12 KB
    __shared__ float lin[R][1152];    // 36.8 KB
    int n0 = blockIdx.x * R;
    int tid = threadIdx.x;

    for (int e = tid; e < R * CSD; e += 256) {
        int r = e / CSD, c = e % CSD;
        sld[r][c] = s[(size_t)(n0 + r) * CSD + c];
    }
    __syncthreads();

    for (int o = tid; o < 1152; o += 256) {
        const float* wrow; float bv;
        if (o < 192)      { wrow = wq   + (size_t)o * CSD;        bv = bq[o]; }
        else if (o < 576) { wrow = wkv  + (size_t)(o-192) * CSD;  bv = bkv[o-192]; }
        else if (o < 720) { wrow = wqp  + (size_t)(o-576) * CSD;  bv = bqp[o-576]; }
        else              { wrow = wkvp + (size_t)(o-720) * CSD;  bv = bkvp[o-720]; }
        float acc[R];
        #pragma unroll
        for (int r = 0; r < R; r++) acc[r] = bv;
        for (int c = 0; c < CSD; c++) {
            float w = wrow[c];
            #pragma unroll
            for (int r = 0; r < R; r++) acc[r] += w * sld[r][c];
        }
        #pragma unroll
        for (int r = 0; r < R; r++) lin[r][o] = acc[r];
    }
    __syncthreads();

    // write q,k,v
    for (int e = tid; e < R * 576; e += 256) {
        int r = e / 576, o = e % 576;
        int nn = n0 + r;
        float val = lin[r][o];
        if (o < 192) {
            q[(size_t)nn * 192 + o] = val;
        } else {
            int oo = o - 192;
            int h = oo / 32, c = oo % 32;
            if (c < 16) k[((size_t)nn * NHD + h) * CHD + c] = val;
            else        v[((size_t)nn * NHD + h) * CHD + (c - 16)] = val;
        }
    }
    // rotate points: qp (48 pts) + kvp (144 pts) per row
    for (int e = tid; e < R * 192; e += 256) {
        int r = e / 192, pt = e % 192;
        int nn = n0 + r;
        const float* Rm = rots + (size_t)nn * 9;
        const float* tr = trans + (size_t)nn * 3;
        float px, py, pz;
        if (pt < 48) {
            px = lin[r][576 + 0*48 + pt];
            py = lin[r][576 + 1*48 + pt];
            pz = lin[r][576 + 2*48 + pt];
        } else {
            int pk = pt - 48;
            px = lin[r][720 + 0*144 + pk];
            py = lin[r][720 + 1*144 + pk];
            pz = lin[r][720 + 2*144 + pk];
        }
        float gx = Rm[0]*px + Rm[1]*py + Rm[2]*pz + tr[0];
        float gy = Rm[3]*px + Rm[4]*py + Rm[5]*pz + tr[1];
        float gz = Rm[6]*px + Rm[7]*py + Rm[8]*pz + tr[2];
        if (pt < 48) {
            int h = pt / 4, pp = pt % 4;
            float* dst = qp + (((size_t)nn * NHD + h) * PQD + pp) * 3;
            dst[0] = gx; dst[1] = gy; dst[2] = gz;
        } else {
            int pk = pt - 48;
            int h = pk / 12, pp = pk % 12;
            if (pp < 4) {
                float* dst = kp + (((size_t)nn * NHD + h) * PQD + pp) * 3;
                dst[0] = gx; dst[1] = gy; dst[2] = gz;
            } else {
                float* dst = vp + (((size_t)nn * NHD + h) * PVD + (pp - 4)) * 3;
                dst[0] = gx; dst[1] = gy; dst[2] = gz;
            }
        }
    }
}

// ---------------------------------------------------------------------------
// K2: fused attention per query row i. 256 threads.
// pass1 (tiled over j): stage p-tile in LDS, bias on the fly + QK dot +
// point-distance -> logits in LDS. Wave-owned softmax (3 heads/wave, no
// internal barriers). pass2a: opair (p row read once, coalesced). pass2b:
// o and op. epilogue: rotate-back, norms, write cat row.
// ---------------------------------------------------------------------------
__global__ __launch_bounds__(256) void k_attn(
    const float* __restrict__ q, const float* __restrict__ k,
    const float* __restrict__ v,
    const float* __restrict__ qp, const float* __restrict__ kp,
    const float* __restrict__ vp,
    const float* __restrict__ p,
    const float* __restrict__ wb, const float* __restrict__ bbias,
    const float* __restrict__ mask, const float* __restrict__ head_w,
    const float* __restrict__ rots, const float* __restrict__ trans,
    float* __restrict__ cat)
{
    __shared__ float lg[NHD][LGP];     // 48.2 KB (padded rows: bank-shift 4/row)
    __shared__ float wbl[NHD][CPD];    // 6 KB
    __shared__ float ptile[32][129];   // 16.5 KB
    __shared__ float qs[NHD][CHD];     // 768 B
    __shared__ float qps[NHD][12];     // 576 B
    __shared__ float coefs[NHD];
    __shared__ float bbl[NHD];
    __shared__ float opst[NHD * PVD * 3];  // 288 floats
    __shared__ float cmb[NHD][CPD];    // 6 KB
    int i   = blockIdx.x;
    int tid = threadIdx.x;
    int lane = tid & 63, wid = tid >> 6;
    float mi = mask[i];

    // ---- init: per-i constants + wb into LDS ----
    for (int e = tid; e < NHD * CPD; e += 256) wbl[e >> 7][e & 127] = wb[e];
    if (tid < NHD * CHD) qs[tid >> 4][tid & 15] = q[(size_t)i * 192 + tid];
    if (tid < NHD * 12)  qps[tid / 12][tid % 12] = qp[(size_t)i * 144 + tid];
    if (tid < NHD) {
        coefs[tid] = -0.5f * logf(1.0f + expf(head_w[tid])) * SQ_PT;
        bbl[tid] = bbias[tid];
    }
    __syncthreads();

    // ---- pass 1: logits, tiled over j in chunks of 32 ----
    for (int t = 0; t < NRES / 32; t++) {
        const float4* psrc = (const float4*)(p + ((size_t)i * NRES + t * 32) * CPD);
        for (int e = tid; e < 1024; e += 256) {
            float4 val = psrc[e];
            int rr = e >> 5, c4 = e & 31;
            ptile[rr][c4*4+0] = val.x; ptile[rr][c4*4+1] = val.y;
            ptile[rr][c4*4+2] = val.z; ptile[rr][c4*4+3] = val.w;
        }
        __syncthreads();
        for (int e = tid; e < NHD * 32; e += 256) {
            int h = e >> 5, jj = e & 31;
            int j = (t << 5) + jj;
            float bsum = 0.f;
            #pragma unroll 8
            for (int c = 0; c < CPD; c++) bsum += ptile[jj][c] * wbl[h][c];
            const float* kj = k + ((size_t)j * NHD + h) * CHD;
            float dot = 0.f;
            #pragma unroll
            for (int c = 0; c < CHD; c++) dot += qs[h][c] * kj[c];
            const float* kpj = kp + ((size_t)j * NHD + h) * PQD * 3;
            float d2 = 0.f;
            #pragma unroll
            for (int pp = 0; pp < PQD; pp++) {
                float dx = qps[h][pp*3]   - kpj[pp*3];
                float dy = qps[h][pp*3+1] - kpj[pp*3+1];
                float dz = qps[h][pp*3+2] - kpj[pp*3+2];
                d2 += dx*dx + dy*dy + dz*dz;
            }
            lg[h][j] = dot * SQ_QK + SQ_B * (bsum + bbl[h]) + coefs[h] * d2
                     + INF_MASK * (mi * mask[j] - 1.0f);
        }
        __syncthreads();
    }
    // (last tile's barrier makes all lg writes visible)

    // ---- softmax: wave-owned heads (wave w owns heads 3w..3w+2), no barriers
    for (int hh = 0; hh < 3; hh++) {
        int h = wid * 3 + hh;
        float m = -1e30f;
        for (int j = lane; j < NRES; j += 64) m = fmaxf(m, lg[h][j]);
        #pragma unroll
        for (int off = 32; off; off >>= 1) m = fmaxf(m, __shfl_xor(m, off));
        float ssum = 0.f;
        for (int j = lane; j < NRES; j += 64) {
            float e = expf(lg[h][j] - m);
            lg[h][j] = e;
            ssum += e;
        }
        #pragma unroll
        for (int off = 32; off; off >>= 1) ssum += __shfl_xor(ssum, off);
        float inv = 1.0f / ssum;
        for (int j = lane; j < NRES; j += 64) lg[h][j] *= inv;
    }
    __syncthreads();

    // ---- pass 2a: opair — read p row exactly once, coalesced ----
    {
        int cp  = tid & 127;
        int rep = tid >> 7;   // 0/1 halves of j
        float acc[NHD];
        #pragma unroll
        for (int h = 0; h < NHD; h++) acc[h] = 0.f;
        const float* prow = p + (size_t)i * NRES * CPD;
        int j0 = rep * 512, j1 = j0 + 512;
        for (int j = j0; j < j1; j++) {
            float pv = prow[(size_t)j * CPD + cp];
            #pragma unroll
            for (int h = 0; h < NHD; h++) acc[h] += lg[h][j] * pv;
        }
        if (rep == 1) {
            #pragma unroll
            for (int h = 0; h < NHD; h++) cmb[h][cp] = acc[h];
        }
        __syncthreads();
        if (rep == 0) {
            #pragma unroll
            for (int h = 0; h < NHD; h++)
                cat[(size_t)i * COUT + 576 + h * CPD + cp] = acc[h] + cmb[h][cp];
        }
    }

    // ---- pass 2b: o (192 entries) and op (288 entries) ----
    for (int e = tid; e < 480; e += 256) {
        float acc = 0.f;
        if (e < 192) {
            int h = e >> 4, c = e & 15;
            const float* vb = v + (size_t)h * CHD + c;
            for (int j = 0; j < NRES; j++) acc += lg[h][j] * vb[(size_t)j * 192];
            cat[(size_t)i * COUT + e] = acc;
        } else {
            int e2 = e - 192;
            int h = e2 / 24, rem = e2 % 24;
            int pvi = rem / 3, x = rem % 3;
            const float* vpb = vp + ((size_t)h * PVD + pvi) * 3 + x;
            for (int j = 0; j < NRES; j++) acc += lg[h][j] * vpb[(size_t)j * 288];
            opst[e2] = acc;
        }
    }
    __syncthreads();

    // ---- epilogue: rotate back op, norms ----
    const float* Rm = rots + (size_t)i * 9;
    const float* tr = trans + (size_t)i * 3;
    for (int pt = tid; pt < 96; pt += 256) {
        float ox = opst[pt*3]   - tr[0];
        float oy = opst[pt*3+1] - tr[1];
        float oz = opst[pt*3+2] - tr[2];
        float lx = Rm[0]*ox + Rm[3]*oy + Rm[6]*oz;
        float ly = Rm[1]*ox + Rm[4]*oy + Rm[7]*oz;
        float lz = Rm[2]*ox + Rm[5]*oy + Rm[8]*oz;
        size_t base = (size_t)i * COUT;
        cat[base + 192 + pt] = lx;
        cat[base + 288 + pt] = ly;
        cat[base + 384 + pt] = lz;
        cat[base + 480 + pt] = sqrtf(lx*lx + ly*ly + lz*lz + 1e-8f);
    }
}

// ---------------------------------------------------------------------------
// K3: s1 = LN1(s + cat @ wo.T + bo). 4 rows per block, 384 threads (o = tid).
// ---------------------------------------------------------------------------
__global__ __launch_bounds__(384) void k_outproj(
    const float* __restrict__ s, const float* __restrict__ cat,
    const float* __restrict__ wo, const float* __restrict__ bo,
    const float* __restrict__ g, const float* __restrict__ b,
    float* __restrict__ s1)
{
    const int R = 4;
    __shared__ float catl[R][COUT];   // 33.8 KB
    __shared__ float vals[R][CSD];    // 6 KB
    __shared__ float wred[6];
    __shared__ float stat[2];
    int n0 = blockIdx.x * R;
    int tid = threadIdx.x;
    int lane = tid & 63, wid = tid >> 6;

    for (int e = tid; e < R * COUT; e += 384) {
        int r = e / COUT, c = e % COUT;
        catl[r][c] = cat[(size_t)(n0 + r) * COUT + c];
    }
    __syncthreads();

    int o = tid;
    float acc[R];
    #pragma unroll
    for (int r = 0; r < R; r++) acc[r] = bo[o];
    const float* wrow = wo + (size_t)o * COUT;
    for (int c = 0; c < COUT; c++) {
        float w = wrow[c];
        #pragma unroll
        for (int r = 0; r < R; r++) acc[r] += w * catl[r][c];
    }
    #pragma unroll
    for (int r = 0; r < R; r++) {
        acc[r] += s[(size_t)(n0 + r) * CSD + o];
        vals[r][o] = acc[r];
    }
    __syncthreads();

    for (int r = 0; r < R; r++) {
        float xv = vals[r][tid];
        float sv = xv;
        #pragma unroll
        for (int off = 32; off; off >>= 1) sv += __shfl_xor(sv, off);
        if (lane == 0) wred[wid] = sv;
        __syncthreads();
        if (tid == 0) {
            float t = 0.f;
            for (int w6 = 0; w6 < 6; w6++) t += wred[w6];
            stat[0] = t / (float)CSD;
        }
        __syncthreads();
        float mean = stat[0];
        float d = xv - mean;
        float sq = d * d;
        #pragma unroll
        for (int off = 32; off; off >>= 1) sq += __shfl_xor(sq, off);
        if (lane == 0) wred[wid] = sq;
        __syncthreads();
        if (tid == 0) {
            float t = 0.f;
            for (int w6 = 0; w6 < 6; w6++) t += wred[w6];
            stat[1] = 1.0f / sqrtf(t / (float)CSD + 1e-5f);
        }
        __syncthreads();
        float inv = stat[1];
        s1[(size_t)(n0 + r) * CSD + tid] = d * inv * g[tid] + b[tid];
        __syncthreads();
    }
}

// ---------------------------------------------------------------------------
// K4: transition MLP + residual + LN2 -> writes s-part of d_out.
// 8 rows per block, 384 threads.
// ---------------------------------------------------------------------------
__global__ __launch_bounds__(384) void k_transition(
    const float* __restrict__ s1,
    const float* __restrict__ w1, const float* __restrict__ b1,
    const float* __restrict__ w2, const float* __restrict__ b2,
    const float* __restrict__ w3, const float* __restrict__ b3,
    const float* __restrict__ g, const float* __restrict__ b,
    float* __restrict__ sout)
{
    const int R = 8;
    __shared__ float A[R][CSD];   // s1 rows (kept for residual)
    __shared__ float Bb[R][CSD];
    __shared__ float Cc[R][CSD];
    __shared__ float vals[R][CSD];
    __shared__ float wred[6];
    __shared__ float stat[2];
    int n0 = blockIdx.x * R;
    int tid = threadIdx.x;
    int lane = tid & 63, wid = tid >> 6;

    for (int e = tid; e < R * CSD; e += 384) {
        int r = e / CSD, c = e % CSD;
        A[r][c] = s1[(size_t)(n0 + r) * CSD + c];
    }
    __syncthreads();

    int o = tid;
    {   // layer 1
        float acc[R];
        #pragma unroll
        for (int r = 0; r < R; r++) acc[r] = b1[o];
        const float* wrow = w1 + (size_t)o * CSD;
        for (int c = 0; c < CSD; c++) {
            float w = wrow[c];
            #pragma unroll
            for (int r = 0; r < R; r++) acc[r] += w * A[r][c];
        }
        #pragma unroll
        for (int r = 0; r < R; r++) Bb[r][o] = fmaxf(acc[r], 0.f);
    }
    __syncthreads();
    {   // layer 2
        float acc[R];
        #pragma unroll
        for (int r = 0; r < R; r++) acc[r] = b2[o];
        const float* wrow = w2 + (size_t)o * CSD;
        for (int c = 0; c < CSD; c++) {
            float w = wrow[c];
            #pragma unroll
            for (int r = 0; r < R; r++) acc[r] += w * Bb[r][c];
        }
        #pragma unroll
        for (int r = 0; r < R; r++) Cc[r][o] = fmaxf(acc[r], 0.f);
    }
    __syncthreads();
    {   // layer 3 + residual
        float acc[R];
        #pragma unroll
        for (int r = 0; r < R; r++) acc[r] = b3[o];
        const float* wrow = w3 + (size_t)o * CSD;
        for (int c = 0; c < CSD; c++) {
            float w = wrow[c];
            #pragma unroll
            for (int r = 0; r < R; r++) acc[r] += w * Cc[r][c];
        }
        #pragma unroll
        for (int r = 0; r < R; r++) vals[r][o] = acc[r] + A[r][o];
    }
    __syncthreads();

    for (int r = 0; r < R; r++) {
        float xv = vals[r][tid];
        float sv = xv;
        #pragma unroll
        for (int off = 32; off; off >>= 1) sv += __shfl_xor(sv, off);
        if (lane == 0) wred[wid] = sv;
        __syncthreads();
        if (tid == 0) {
            float t = 0.f;
            for (int w6 = 0; w6 < 6; w6++) t += wred[w6];
            stat[0] = t / (float)CSD;
        }
        __syncthreads();
        float mean = stat[0];
        float d = xv - mean;
        float sq = d * d;
        #pragma unroll
        for (int off = 32; off; off >>= 1) sq += __shfl_xor(sq, off);
        if (lane == 0) wred[wid] = sq;
        __syncthreads();
        if (tid == 0) {
            float t = 0.f;
            for (int w6 = 0; w6 < 6; w6++) t += wred[w6];
            stat[1] = 1.0f / sqrtf(t / (float)CSD + 1e-5f);
        }
        __syncthreads();
        float inv = stat[1];
        sout[(size_t)(n0 + r) * CSD + tid] = d * inv * g[tid] + b[tid];
        __syncthreads();
    }
}

// ---------------------------------------------------------------------------
// K5: pose update. 4 rows per block (one wave per row), 256 threads.
// ---------------------------------------------------------------------------
__global__ __launch_bounds__(256) void k_pose(
    const float* __restrict__ s2, const float* __restrict__ rots,
    const float* __restrict__ trans,
    const float* __restrict__ wbb, const float* __restrict__ bbb,
    float* __restrict__ out_rots, float* __restrict__ out_trans)
{
    int row = blockIdx.x * 4 + (threadIdx.x >> 6);
    int lane = threadIdx.x & 63;
    const float* sr = s2 + (size_t)row * CSD;
    float u[6];
    #pragma unroll
    for (int e = 0; e < 6; e++) {
        float acc = 0.f;
        for (int c = lane; c < CSD; c += 64) acc += sr[c] * wbb[(size_t)e * CSD + c];
        #pragma unroll
        for (int off = 32; off; off >>= 1) acc += __shfl_xor(acc, off);
        u[e] = acc + bbb[e];
    }
    if (lane == 0) {
        float qx = u[0], qy = u[1], qz = u[2];
        float inv = 1.0f / sqrtf(1.0f + qx*qx + qy*qy + qz*qz);
        float w = inv, x = qx*inv, y = qy*inv, z = qz*inv;
        float ru[9];
        ru[0] = w*w + x*x - y*y - z*z; ru[1] = 2*(x*y - w*z);       ru[2] = 2*(x*z + w*y);
        ru[3] = 2*(x*y + w*z);         ru[4] = w*w - x*x + y*y - z*z; ru[5] = 2*(y*z - w*x);
        ru[6] = 2*(x*z - w*y);         ru[7] = 2*(y*z + w*x);       ru[8] = w*w - x*x - y*y + z*z;
        const float* Rm = rots + (size_t)row * 9;
        float* Ro = out_rots + (size_t)row * 9;
        #pragma unroll
        for (int xx = 0; xx < 3; xx++) {
            #pragma unroll
            for (int zz = 0; zz < 3; zz++) {
                Ro[xx*3 + zz] = Rm[xx*3+0]*ru[0*3+zz] + Rm[xx*3+1]*ru[1*3+zz]
                              + Rm[xx*3+2]*ru[2*3+zz];
            }
        }
        const float* tr = trans + (size_t)row * 3;
        float* To = out_trans + (size_t)row * 3;
        #pragma unroll
        for (int xx = 0; xx < 3; xx++) {
            To[xx] = Rm[xx*3+0]*u[3] + Rm[xx*3+1]*u[4] + Rm[xx*3+2]*u[5] + tr[xx];
        }
    }
}

// ---------------------------------------------------------------------------
extern "C" void kernel_launch(void* const* d_in, const int* in_sizes, int n_in,
                              void* d_out, int out_size, void* d_ws, size_t ws_size,
                              hipStream_t stream)
{
    const float* s     = (const float*)d_in[0];
    const float* p     = (const float*)d_in[1];
    const float* rots  = (const float*)d_in[2];
    const float* trans = (const float*)d_in[3];
    const float* mask  = (const float*)d_in[4];
    const float* wq    = (const float*)d_in[5];
    const float* bq    = (const float*)d_in[6];
    const float* wkv   = (const float*)d_in[7];
    const float* bkv   = (const float*)d_in[8];
    const float* wqp   = (const float*)d_in[9];
    const float* bqp   = (const float*)d_in[10];
    const float* wkvp  = (const float*)d_in[11];
    const float* bkvp  = (const float*)d_in[12];
    const float* wb    = (const float*)d_in[13];
    const float* bbias = (const float*)d_in[14];
    const float* head_w= (const float*)d_in[15];
    const float* wo    = (const float*)d_in[16];
    const float* bo    = (const float*)d_in[17];
    const float* ln1_g = (const float*)d_in[18];
    const float* ln1_b = (const float*)d_in[19];
    const float* t_w1  = (const float*)d_in[20];
    const float* t_b1  = (const float*)d_in[21];
    const float* t_w2  = (const float*)d_in[22];
    const float* t_b2  = (const float*)d_in[23];
    const float* t_w3  = (const float*)d_in[24];
    const float* t_b3  = (const float*)d_in[25];
    const float* ln2_g = (const float*)d_in[26];
    const float* ln2_b = (const float*)d_in[27];
    const float* wbb   = (const float*)d_in[28];
    const float* bbb   = (const float*)d_in[29];

    float* ws = (float*)d_ws;
    float* q   = ws;                    // 1024*192
    float* k   = q   + 196608;
    float* v   = k   + 196608;
    float* qp  = v   + 196608;          // 1024*144
    float* kp  = qp  + 147456;
    float* vp  = kp  + 147456;          // 1024*288
    float* cat = vp  + 294912;          // 1024*2112
    float* s1  = cat + 2162688;         // 1024*384
    // total 3,735,552 floats ≈ 14.2 MB

    float* out   = (float*)d_out;
    float* out_s = out;                        // 1024*384
    float* out_r = out + 1024*384;             // 1024*9
    float* out_t = out + 1024*384 + 1024*9;    // 1024*3

    k_proj<<<NRES/8, 256, 0, stream>>>(s, rots, trans, wq, bq, wkv, bkv,
                                       wqp, bqp, wkvp, bkvp, q, k, v, qp, kp, vp);
    k_attn<<<NRES, 256, 0, stream>>>(q, k, v, qp, kp, vp, p, wb, bbias, mask,
                                     head_w, rots, trans, cat);
    k_outproj<<<NRES/4, 384, 0, stream>>>(s, cat, wo, bo, ln1_g, ln1_b, s1);
    k_transition<<<NRES/8, 384, 0, stream>>>(s1, t_w1, t_b1, t_w2, t_b2,
                                             t_w3, t_b3, ln2_g, ln2_b, out_s);
    k_pose<<<NRES/4, 256, 0, stream>>>(out_s, rots, trans, wbb, bbb, out_r, out_t);
}